// Round 13
// baseline (1254.974 us; speedup 1.0000x reference)
//
#include <hip/hip_runtime.h>
#include <hip/hip_bf16.h>

typedef _Float16 f16;
typedef _Float16 half8 __attribute__((ext_vector_type(8)));
typedef float f32x4 __attribute__((ext_vector_type(4)));
typedef int i32x4 __attribute__((ext_vector_type(4)));

// B=32, S=1024, D=256, H=256, 4H=1024
// Scan r13 (hybrid, shared-register): waves 0-11 -> h-cols 0-191 via i8 MFMA
// (3 waves/SIMD, 48 MFMA/SIMD/step); waves 12-15 -> h-cols 192-255 via sdot4
// on the VALU pipe (1 wave/SIMD), one (gate,col) per lane. ONE shared 64-reg
// array ub[16] holds U in role-specific layout (r11 failed because two
// disjoint 64-reg arrays blew the 128-reg budget -> scratch spill).

// ---------------- prep: int8 quantization of U, both layouts ----------------
// UQm (all 64 tiles): uint4 idx ((dir*64 + tile)*4 + ks)*64 + kg*16 + colr
//   packs k = ks*64 + kg*16 + {0..15} for col = tile*16 + colr.
// UQd (cols with hc>=192): dword (dir*256 + cc)*64 + kk packs k=4kk..4kk+3
//   for gate-col cc = gate*64 + (hc-192).
__global__ void prep_uq_kernel(const float* __restrict__ Uf, const float* __restrict__ Ur,
                               unsigned int* __restrict__ UQm, unsigned int* __restrict__ UQd,
                               float* __restrict__ Uscale)
{
    int idx = blockIdx.x * 256 + threadIdx.x;   // (dir, c)
    if (idx >= 2048) return;
    int dir = idx >> 10, c = idx & 1023;
    const float* U = dir ? Ur : Uf;
    float m = 0.f;
    for (int k = 0; k < 256; ++k) m = fmaxf(m, fabsf(U[k * 1024 + c]));
    float sinv = (m > 0.f) ? 127.f / m : 0.f;
    int tile = c >> 4, colr = c & 15;
    uint4* UQm4 = (uint4*)UQm;
    for (int ks = 0; ks < 4; ++ks) {
        #pragma unroll
        for (int kg = 0; kg < 4; ++kg) {
            unsigned int w[4];
            #pragma unroll
            for (int d = 0; d < 4; ++d) {
                unsigned int wd = 0;
                #pragma unroll
                for (int e = 0; e < 4; ++e) {
                    int k = ks * 64 + kg * 16 + d * 4 + e;
                    int q = __float2int_rn(U[k * 1024 + c] * sinv);
                    wd |= ((unsigned int)(q & 0xff)) << (8 * e);
                }
                w[d] = wd;
            }
            UQm4[((size_t)((dir * 64 + tile) * 4 + ks)) * 64 + kg * 16 + colr] =
                make_uint4(w[0], w[1], w[2], w[3]);
        }
    }
    int g = c >> 8, hc = c & 255;
    if (hc >= 192) {                             // dot layout for last 64 h-cols
        int cc = g * 64 + (hc - 192);
        for (int kk = 0; kk < 64; ++kk) {
            unsigned int wd = 0;
            #pragma unroll
            for (int e = 0; e < 4; ++e) {
                int q = __float2int_rn(U[(kk * 4 + e) * 1024 + c] * sinv);
                wd |= ((unsigned int)(q & 0xff)) << (8 * e);
            }
            UQd[((size_t)(dir * 256 + cc)) * 64 + kk] = wd;
        }
    }
    Uscale[idx] = m / (127.f * 127.f);  // U-scale * h-dequant(1/127)
}

// ---------------- projection GEMM (unchanged, proven) -----------------------
__global__ __launch_bounds__(256) void proj_gemm_kernel(
    const float* __restrict__ x, const float* __restrict__ Wf, const float* __restrict__ Wr,
    const float* __restrict__ bfw, const float* __restrict__ brw, f16* __restrict__ G)
{
    const int nt = blockIdx.x;
    const int mt = blockIdx.y;
    const int m0 = mt * 128, n0 = nt * 128;
    const int dir = n0 >> 10, nin0 = n0 & 1023;
    const float* W   = dir ? Wr : Wf;
    const float* bia = dir ? brw : bfw;
    __shared__ f16 Asm[128][40];
    __shared__ f16 Bsm[128][40];
    const int t = threadIdx.x;
    const int lane = t & 63, wave = t >> 6;
    const int wr = wave >> 1, wc = wave & 1;
    f32x4 acc[4][4] = {};
    for (int k0 = 0; k0 < 256; k0 += 32) {
        #pragma unroll
        for (int e = 0; e < 16; ++e) {
            int idx = e * 256 + t;
            int r = idx >> 5, kk = idx & 31;
            Asm[r][kk] = (f16)x[(size_t)(m0 + r) * 256 + (k0 + kk)];
        }
        #pragma unroll
        for (int e = 0; e < 16; ++e) {
            int idx = e * 256 + t;
            int col = idx & 127, kr = idx >> 7;
            Bsm[col][kr] = (f16)W[(size_t)(k0 + kr) * 1024 + (nin0 + col)];
        }
        __syncthreads();
        const int l15 = lane & 15, kb = (lane >> 4) * 8;
        half8 af[4], bfr[4];
        #pragma unroll
        for (int fr = 0; fr < 4; ++fr) af[fr]  = *(const half8*)&Asm[wr * 64 + fr * 16 + l15][kb];
        #pragma unroll
        for (int fc = 0; fc < 4; ++fc) bfr[fc] = *(const half8*)&Bsm[wc * 64 + fc * 16 + l15][kb];
        #pragma unroll
        for (int fr = 0; fr < 4; ++fr)
            #pragma unroll
            for (int fc = 0; fc < 4; ++fc)
                acc[fr][fc] = __builtin_amdgcn_mfma_f32_16x16x32_f16(af[fr], bfr[fc], acc[fr][fc], 0, 0, 0);
        __syncthreads();
    }
    const int row4 = (lane >> 4) * 4, c15 = lane & 15;
    #pragma unroll
    for (int fr = 0; fr < 4; ++fr)
        #pragma unroll
        for (int fc = 0; fc < 4; ++fc) {
            int rbase = m0 + wr * 64 + fr * 16 + row4;
            int cidx  = n0 + wc * 64 + fc * 16 + c15;
            float bv = bia[cidx & 1023];
            #pragma unroll
            for (int i = 0; i < 4; ++i)
                G[(size_t)(rbase + i) * 2048 + cidx] = (f16)(acc[fr][fc][i] + bv);
        }
}

// ---------------- scan ------------------------------------------------------
__device__ __forceinline__ int dot4i8(unsigned int a, unsigned int b, int c) {
#if __has_builtin(__builtin_amdgcn_sdot4)
    return __builtin_amdgcn_sdot4(a, b, c, false);
#else
    c += (int)(signed char)(a)       * (int)(signed char)(b);
    c += (int)(signed char)(a >> 8)  * (int)(signed char)(b >> 8);
    c += (int)(signed char)(a >> 16) * (int)(signed char)(b >> 16);
    c += (int)(signed char)(a >> 24) * (int)(signed char)(b >> 24);
    return c;
#endif
}

template<int PAT>
__device__ __forceinline__ float qb(float v) {   // quad_perm broadcast
    return __int_as_float(__builtin_amdgcn_mov_dpp(__float_as_int(v), PAT, 0xF, 0xF, true));
}

#define LGKM_BARRIER() do { \
    asm volatile("s_waitcnt lgkmcnt(0)\n\ts_barrier" ::: "memory"); \
    __builtin_amdgcn_sched_barrier(0); \
} while (0)

__global__
__attribute__((amdgpu_flat_work_group_size(1024, 1024)))
__attribute__((amdgpu_waves_per_eu(4, 4)))
void scan_kernel(
    const f16* __restrict__ G, const unsigned int* __restrict__ UQm,
    const unsigned int* __restrict__ UQd, const float* __restrict__ Uscale,
    float* __restrict__ out)
{
    const int wg = blockIdx.x;
    const int dir = wg >> 5, b = wg & 31;
    const int tid = threadIdx.x;
    const int wave = tid >> 6, lane = tid & 63;
    const bool mw = (wave < 12);                    // mfma role (3 waves/SIMD)
    const int colq = lane >> 2, gate = lane & 3;
    const int hc = mw ? (wave * 16 + colq) : (192 + (wave - 12) * 16 + colq);

    __shared__ __align__(16) unsigned int hq[128];  // 2 bufs x 256B int8 h
    if (tid < 64) hq[tid] = 0u;                     // buf0 = h0 = 0

    // ONE shared 64-reg U array; layout differs by wave role.
    i32x4 ub[16];
    if (mw) {
        const i32x4* UQm4 = (const i32x4*)UQm;
        #pragma unroll
        for (int g = 0; g < 4; ++g)
            #pragma unroll
            for (int ks = 0; ks < 4; ++ks)
                ub[g * 4 + ks] =
                    UQm4[((size_t)((dir * 64 + g * 16 + wave) * 4 + ks)) * 64 + lane];
    } else {
        const int cc = gate * 64 + (wave - 12) * 16 + colq;
        const i32x4* up = (const i32x4*)(UQd + ((size_t)(dir * 256 + cc)) * 64);
        #pragma unroll
        for (int kkk = 0; kkk < 16; ++kkk)
            ub[kkk] = up[kkk];
    }

    const float uscl = Uscale[dir * 1024 + gate * 256 + hc];

    // per-lane xW stream for (gate, hc)
    const f16* Gl = G + (size_t)b * 1024 * 2048 + dir * 1024 + gate * 256 + hc;
    float* outp = out + (size_t)b * 1024 * 512 + dir * 256 + hc;
    const int s0 = dir ? 1023 : 0;
    float xw = (float)Gl[(size_t)s0 * 2048];
    float c_state = 0.f;                            // replicated per quad
    __syncthreads();

    const char* hqb = (const char*)hq;
    signed char* hqw = (signed char*)hq;
    const int arow = (lane >> 4) << 4;              // A-frag byte offset
    const int baddr = lane & ~3;                    // bpermute byte addr
    int p = 0;

    for (int t = 0; t < 1024; ++t) {
        const int s  = dir ? (1023 - t) : t;
        const int tn = (t < 1023) ? (t + 1) : t;
        const int sn = dir ? (1023 - tn) : tn;
        f16 xn = Gl[(size_t)sn * 2048];             // prefetch next xW

        float pre;
        if (mw) {
            // h @ U, exact i32; A = h broadcast, all C rows identical
            i32x4 acc0 = {0,0,0,0}, acc1 = {0,0,0,0}, acc2 = {0,0,0,0}, acc3 = {0,0,0,0};
            #pragma unroll
            for (int ks = 0; ks < 4; ++ks) {
                i32x4 a = *(const i32x4*)(hqb + p * 256 + ks * 64 + arow);
                acc0 = __builtin_amdgcn_mfma_i32_16x16x64_i8(a, ub[ 0 + ks], acc0, 0, 0, 0);
                acc1 = __builtin_amdgcn_mfma_i32_16x16x64_i8(a, ub[ 4 + ks], acc1, 0, 0, 0);
                acc2 = __builtin_amdgcn_mfma_i32_16x16x64_i8(a, ub[ 8 + ks], acc2, 0, 0, 0);
                acc3 = __builtin_amdgcn_mfma_i32_16x16x64_i8(a, ub[12 + ks], acc3, 0, 0, 0);
            }
            // lane holds pre(col lane&15, gate g) in acc_g[0]; redistribute
            int r0 = __builtin_amdgcn_ds_bpermute(baddr, acc0[0]);
            int r1 = __builtin_amdgcn_ds_bpermute(baddr, acc1[0]);
            int r2 = __builtin_amdgcn_ds_bpermute(baddr, acc2[0]);
            int r3 = __builtin_amdgcn_ds_bpermute(baddr, acc3[0]);
            int iv01 = (gate & 1) ? r1 : r0;
            int iv23 = (gate & 1) ? r3 : r2;
            int iv   = (gate & 2) ? iv23 : iv01;
            pre = (float)iv * uscl + xw;
        } else {
            // sdot4 over my (gate,col)'s U column (chunked, r5-verified)
            const uint4* hp4 = (const uint4*)(hqb + p * 256);
            int i0 = 0, i1 = 0, i2 = 0, i3 = 0;
            #pragma unroll
            for (int ch = 0; ch < 4; ++ch) {
                uint4 ha = hp4[ch * 4 + 0];
                uint4 hb = hp4[ch * 4 + 1];
                uint4 hcv = hp4[ch * 4 + 2];
                uint4 hd = hp4[ch * 4 + 3];
                const i32x4 u0 = ub[ch * 4 + 0], u1 = ub[ch * 4 + 1];
                const i32x4 u2 = ub[ch * 4 + 2], u3 = ub[ch * 4 + 3];
                i0 = dot4i8((unsigned)u0[0], ha.x, i0);
                i1 = dot4i8((unsigned)u0[1], ha.y, i1);
                i2 = dot4i8((unsigned)u0[2], ha.z, i2);
                i3 = dot4i8((unsigned)u0[3], ha.w, i3);
                i0 = dot4i8((unsigned)u1[0], hb.x, i0);
                i1 = dot4i8((unsigned)u1[1], hb.y, i1);
                i2 = dot4i8((unsigned)u1[2], hb.z, i2);
                i3 = dot4i8((unsigned)u1[3], hb.w, i3);
                i0 = dot4i8((unsigned)u2[0], hcv.x, i0);
                i1 = dot4i8((unsigned)u2[1], hcv.y, i1);
                i2 = dot4i8((unsigned)u2[2], hcv.z, i2);
                i3 = dot4i8((unsigned)u2[3], hcv.w, i3);
                i0 = dot4i8((unsigned)u3[0], hd.x, i0);
                i1 = dot4i8((unsigned)u3[1], hd.y, i1);
                i2 = dot4i8((unsigned)u3[2], hd.z, i2);
                i3 = dot4i8((unsigned)u3[3], hd.w, i3);
                __builtin_amdgcn_sched_barrier(0);
            }
            pre = (float)((i0 + i1) + (i2 + i3)) * uscl + xw;
        }

        // unified quad-gate epilogue (r10/r12-verified)
        float a2 = (gate == 2) ? (pre + pre) : -pre;
        float E  = __expf(a2);
        float r  = __fdividef(1.f, E + 1.f);
        float v  = (gate == 2) ? (1.f - 2.f * r) : r;
        float b0 = qb<0x00>(v), b1 = qb<0x55>(v), b2 = qb<0xAA>(v), b3 = qb<0xFF>(v);
        c_state = b1 * c_state + b0 * b2;
        float e2 = __expf(c_state + c_state);
        float th = 1.f - __fdividef(2.f, e2 + 1.f);
        float h  = b3 * th;

        if (gate == 0) outp[(size_t)s * 512] = h;
        if (gate == 1) hqw[(p ^ 1) * 256 + hc] = (signed char)__float2int_rn(h * 127.f);

        LGKM_BARRIER();                             // new h visible to all
        p ^= 1;
        xw = (float)xn;
    }
}

extern "C" void kernel_launch(void* const* d_in, const int* in_sizes, int n_in,
                              void* d_out, int out_size, void* d_ws, size_t ws_size,
                              hipStream_t stream) {
    const float* x  = (const float*)d_in[0];
    const float* Wf = (const float*)d_in[1];
    const float* Uf = (const float*)d_in[2];
    const float* bf = (const float*)d_in[3];
    const float* Wr = (const float*)d_in[4];
    const float* Ur = (const float*)d_in[5];
    const float* br = (const float*)d_in[6];
    float* out = (float*)d_out;

    char* ws = (char*)d_ws;
    unsigned int* UQm = (unsigned int*)ws;                        // 512 KB
    unsigned int* UQd = (unsigned int*)(ws + (size_t)512 * 1024); // 128 KB
    float* Uscale     = (float*)(ws + (size_t)768 * 1024);        // 8 KB
    f16* G            = (f16*)(ws + (size_t)1024 * 1024);         // 128 MB

    prep_uq_kernel<<<8, 256, 0, stream>>>(Uf, Ur, UQm, UQd, Uscale);
    dim3 gg(16, 256);
    proj_gemm_kernel<<<gg, 256, 0, stream>>>(x, Wf, Wr, bf, br, G);
    scan_kernel<<<64, 1024, 0, stream>>>(G, UQm, UQd, Uscale, out);
}